// Round 6
// baseline (3538.214 us; speedup 1.0000x reference)
//
#include <hip/hip_runtime.h>

#define Bb 256
#define Tt 256
#define Ee 64
#define Nn 512
#define Vv 128
#define Gg 2048  // 4*N

typedef __attribute__((ext_vector_type(8))) _Float16 fp16x8;
typedef __attribute__((ext_vector_type(4))) float f32x4;

__device__ __forceinline__ unsigned short f2h(float f) {  // fp32 -> fp16 bits (RTE)
  union { _Float16 h; unsigned short u; } cv;
  cv.h = (_Float16)f;
  return cv.u;
}

__device__ __forceinline__ float sigm_fast(float x) { return 1.f / (1.f + __expf(-x)); }
// saturates correctly at +/-inf; abs err ~1e-7 (negligible vs fp16 budget)
__device__ __forceinline__ float tanh_fast(float x) { return 1.f - 2.f / (1.f + __expf(2.f * x)); }

// Kernel 1: proj[v][g] = bias[g] + sum_e emb[v][e]*Wx[e][g]; also zero barrier ctrs.
__global__ void proj_kernel(const float* __restrict__ emb, const float* __restrict__ Wx,
                            const float* __restrict__ bias, float* __restrict__ proj,
                            unsigned int* __restrict__ ctr) {
  const int v = blockIdx.x;
  __shared__ float el[Ee];
  if (threadIdx.x < Ee) el[threadIdx.x] = emb[v * Ee + threadIdx.x];
  __syncthreads();
  for (int g = threadIdx.x; g < Gg; g += blockDim.x) {
    float s = bias[g];
#pragma unroll
    for (int e = 0; e < Ee; ++e) s = fmaf(el[e], Wx[e * Gg + g], s);
    proj[v * Gg + g] = s;
  }
  if (v == 0) ctr[threadIdx.x] = 0u;  // re-zeroed EVERY launch (d_ws is poisoned 0xAA)
}

// Kernel 2: persistent LSTM. 256 blocks x 512 threads, 1 block/CU (cooperative).
// block -> (bg = blockIdx&7: batch rows [bg*32,+32)) x (nc = blockIdx>>3: hidden [nc*16,+16))
// 8 independent recurrences; per-step 32-block group barrier (monotone ctr, agent scope).
// Matmul operands are fp16 (11-bit precision: 8x lower rounding error than bf16 —
// round-5 bf16 version failed validation 7.8e-3 vs 7.03e-3; fp16 predicts ~1e-3).
// State (c), gates, proj, and the dense logits GEMM remain fp32.
//
// Buffering proof sketch:
//  - hx (fp16 h, 2 buffers): read at iter t BEFORE our release-add for barrier t, so
//    peers are at most at iter t (writing buf t&1); buf (t-1)&1 is stable.  OK
//  - hfp (f32 h, 3 buffers): read in the barrier WINDOW of iter t (after our release-add),
//    so a fast peer may be at iter t+1 writing buf (t+1)%3; we read (t-1)%3 != (t+1)%3. OK
//  - dl (dense partials, 2 parity buffers): window(t) writes parity (t+1)&1 [= P(t-1)];
//    window(t+1) finalizes from parity (t+1)&1; writer/reader separated by sync4/sync1..3.
//
// LDS time-share (64 KB total):
//   phase 1 (init only): Whs 64 KB staging for Wh->VGPR hoist.
//   phase 2 (loop):      hl 32 KB | zl 8.5 KB | dl 4 KB | Wdl 8 KB  (= 52.75 KB).
__launch_bounds__(512, 2)  // 8 waves = 2/SIMD -> compiler caps 256 VGPR (launchability)
__global__ void lstm_kernel(const int* __restrict__ X, const float* __restrict__ h0,
                            const float* __restrict__ c0, const float* __restrict__ Wh,
                            const float* __restrict__ Wd, const float* __restrict__ bd,
                            const float* __restrict__ proj, float* __restrict__ hfp,
                            unsigned short* __restrict__ hx, unsigned int* __restrict__ ctr,
                            float* __restrict__ out) {
  extern __shared__ char smem[];
  short* Whs = (short*)smem;             // phase 1: [64 col][64 slot][8] fp16 (64 KB)
  short* hl  = (short*)smem;             // phase 2: [32 row][64 slot][8] fp16 (32 KB)
  float* zl  = (float*)(smem + 32768);   // phase 2: [32][68] f32 z tile      (8704 B)
  float* dl  = (float*)(smem + 41472);   // phase 2: [2][512] f32 dense scratch (4 KB)
  float* Wdl = (float*)(smem + 45568);   // phase 2: [512 k][4 v] f32         (8 KB)

  const int tid = threadIdx.x;
  const int bg = blockIdx.x & 7;
  const int nc = blockIdx.x >> 3;
  const int nbase = nc << 4;
  const int vbase = nc << 2;
  const int grow0 = bg << 5;

  // ---- phase 1: Wh slice -> LDS fp16, swizzled [col][k8^(col&7)][k&7] ----
  for (int i = tid; i < 64 * 512; i += 512) {
    int col = i & 63;
    int k = i >> 6;
    int zc = (col >> 4) * Nn + nbase + (col & 15);  // gate*N + nbase + nl
    unsigned short w = f2h(Wh[k * Gg + zc]);
    int unit = col * 64 + ((k >> 3) ^ (col & 7));
    ((unsigned short*)Whs)[unit * 8 + (k & 7)] = w;
  }
  __syncthreads();

  // mfma ids: 8 waves = 2 b-tiles x 4 gates
  const int w = tid >> 6, lane = tid & 63;
  const int btile = w & 1, gate = w >> 1;
  const int arow = (btile << 4) + (lane & 15);
  const int bcol = (gate << 4) + (lane & 15);
  const int kg = lane >> 4;

  // hoist this wave's persistent B-fragments (Wh) into registers: 64 VGPR/lane
  fp16x8 bfrag[16];
#pragma unroll
  for (int ks = 0; ks < 16; ++ks) {
    int slot = ks * 4 + kg;
    bfrag[ks] = ((const fp16x8*)Whs)[bcol * 64 + (slot ^ (bcol & 7))];
  }
  __syncthreads();  // phase 1 reads done; phase 2 may now overwrite smem

  // ---- phase 2 init ----
  for (int i = tid; i < 512 * 4; i += 512)
    Wdl[i] = Wd[(i >> 2) * Vv + vbase + (i & 3)];

  // update-phase ids: thread owns one (b,n) cell; c-state lives in a register
  const int ub = tid >> 4;  // 0..31
  const int un = tid & 15;  // 0..15
  float c = c0[(grow0 + ub) * Nn + nbase + un];

  // dense ids: thread = (b=tid>>4, v=(tid>>2)&3, kq=tid&3)
  const int db = tid >> 4, dv = (tid >> 2) & 3, dq = tid & 3;
  const float bdv = bd[vbase + (tid & 3)];
  const int* xrow = X + (grow0 + ub) * Tt;
  unsigned int* const myctr = &ctr[bg * 32];

#pragma unroll 1
  for (int t = 0; t < Tt; ++t) {
    const int curb = t & 1;  // hx buffer parity

    // hoisted gate-input loads: latency hidden under staging + sync(1) + MFMA
    const int vch = xrow[t];
    const float* pr = proj + (size_t)vch * Gg + nbase + un;
    const float p_i = pr[0 * Nn], p_f = pr[1 * Nn], p_g = pr[2 * Nn], p_o = pr[3 * Nn];

    // ---- stage h_prev (fp16) -> hl (swizzled) ----
    if (t == 0) {
#pragma unroll
      for (int ci = tid; ci < 2048; ci += 512) {
        int row = ci >> 6, slot = ci & 63;
        const float* src = h0 + (grow0 + row) * Nn + slot * 8;
        fp16x8 v;
#pragma unroll
        for (int j = 0; j < 8; ++j) v[j] = (_Float16)src[j];
        ((fp16x8*)hl)[row * 64 + (slot ^ (row & 7))] = v;
      }
    } else {
      const fp16x8* src = (const fp16x8*)(hx + (size_t)(curb ^ 1) * Bb * Nn);
#pragma unroll
      for (int ci = tid; ci < 2048; ci += 512) {  // 4 independent 16B L2 loads in flight
        int row = ci >> 6, slot = ci & 63;
        ((fp16x8*)hl)[row * 64 + (slot ^ (row & 7))] = src[(grow0 + row) * 64 + slot];
      }
    }
    __syncthreads();  // (1) hl ready

    // ---- MFMA: z[32b][64c] += h[32b][512k] @ WhSlice ; quad acc -> 4-deep chains ----
    f32x4 a0 = {0.f, 0.f, 0.f, 0.f}, a1 = {0.f, 0.f, 0.f, 0.f};
    f32x4 a2 = {0.f, 0.f, 0.f, 0.f}, a3 = {0.f, 0.f, 0.f, 0.f};
#pragma unroll
    for (int ks = 0; ks < 16; ks += 4) {
      fp16x8 h0v = ((const fp16x8*)hl)[arow * 64 + (((ks + 0) * 4 + kg) ^ (arow & 7))];
      fp16x8 h1v = ((const fp16x8*)hl)[arow * 64 + (((ks + 1) * 4 + kg) ^ (arow & 7))];
      fp16x8 h2v = ((const fp16x8*)hl)[arow * 64 + (((ks + 2) * 4 + kg) ^ (arow & 7))];
      fp16x8 h3v = ((const fp16x8*)hl)[arow * 64 + (((ks + 3) * 4 + kg) ^ (arow & 7))];
      a0 = __builtin_amdgcn_mfma_f32_16x16x32_f16(h0v, bfrag[ks + 0], a0, 0, 0, 0);
      a1 = __builtin_amdgcn_mfma_f32_16x16x32_f16(h1v, bfrag[ks + 1], a1, 0, 0, 0);
      a2 = __builtin_amdgcn_mfma_f32_16x16x32_f16(h2v, bfrag[ks + 2], a2, 0, 0, 0);
      a3 = __builtin_amdgcn_mfma_f32_16x16x32_f16(h3v, bfrag[ks + 3], a3, 0, 0, 0);
    }

    // ---- write z tile (C layout: col=lane&15, row=(lane>>4)*4+j) ----
#pragma unroll
    for (int j = 0; j < 4; ++j)
      zl[((btile << 4) + ((lane >> 4) << 2) + j) * 68 + (gate << 4) + (lane & 15)] =
          (a0[j] + a1[j]) + (a2[j] + a3[j]);
    __syncthreads();  // (2) zl ready

    // ---- gate update (fp32); h -> hfp[t%3] (f32) + hx[t&1] (fp16) ----
    {
      float zi = zl[ub * 68 + 0 + un] + p_i;
      float zf = zl[ub * 68 + 16 + un] + p_f;
      float zg = zl[ub * 68 + 32 + un] + p_g;
      float zo = zl[ub * 68 + 48 + un] + p_o;
      float ii = sigm_fast(zi);
      float ff = sigm_fast(zf);
      float gg = tanh_fast(zg);
      float oo = sigm_fast(zo);
      c = ff * c + ii * gg;
      float h = oo * tanh_fast(c);
      size_t off = (size_t)(grow0 + ub) * Nn + nbase + un;
      hfp[(size_t)(t % 3) * Bb * Nn + off] = h;
      hx[(size_t)curb * Bb * Nn + off] = f2h(h);
    }
    __syncthreads();  // (3) all waves' h stores drained (vmcnt 0) before release

    // ==== barrier window: release-add, then useful work, then relaxed spin ====
    if (tid == 0) {  // publish our h[t] (L2 writeback) + signal
      __hip_atomic_fetch_add(myctr, 1u, __ATOMIC_RELEASE, __HIP_MEMORY_SCOPE_AGENT);
    }
    // dense finalize: logits[t-2] (partials P(t-2) live in dl parity t&1)
    if (t >= 2 && tid < 128) {
      const float* dlR = dl + (t & 1) * 512;
      float s = dlR[tid * 4] + dlR[tid * 4 + 1] + dlR[tid * 4 + 2] + dlR[tid * 4 + 3] + bdv;
      __builtin_nontemporal_store(
          s, &out[((size_t)(grow0 + (tid >> 2)) * Tt + (t - 2)) * Vv + vbase + (tid & 3)]);
    }
    // dense partials: P(t-1) = h[t-1] @ Wd  (hfp buf (t-1)%3: stable, see proof sketch)
    if (t >= 1) {
      const float* hrow = hfp + (size_t)((t - 1) % 3) * Bb * Nn + (grow0 + db) * Nn;
      float s0 = 0.f, s1 = 0.f, s2 = 0.f, s3 = 0.f;
      const float4* h4p = (const float4*)hrow + dq * 32;
#pragma unroll 8
      for (int k4 = 0; k4 < 32; k4 += 4) {
        float4 ha = h4p[k4 + 0], hb = h4p[k4 + 1], hc = h4p[k4 + 2], hd = h4p[k4 + 3];
        int kb = (dq * 32 + k4) * 4;
        s0 = fmaf(ha.x, Wdl[(kb + 0) * 4 + dv], s0);
        s0 = fmaf(ha.y, Wdl[(kb + 1) * 4 + dv], s0);
        s0 = fmaf(ha.z, Wdl[(kb + 2) * 4 + dv], s0);
        s0 = fmaf(ha.w, Wdl[(kb + 3) * 4 + dv], s0);
        s1 = fmaf(hb.x, Wdl[(kb + 4) * 4 + dv], s1);
        s1 = fmaf(hb.y, Wdl[(kb + 5) * 4 + dv], s1);
        s1 = fmaf(hb.z, Wdl[(kb + 6) * 4 + dv], s1);
        s1 = fmaf(hb.w, Wdl[(kb + 7) * 4 + dv], s1);
        s2 = fmaf(hc.x, Wdl[(kb + 8) * 4 + dv], s2);
        s2 = fmaf(hc.y, Wdl[(kb + 9) * 4 + dv], s2);
        s2 = fmaf(hc.z, Wdl[(kb + 10) * 4 + dv], s2);
        s2 = fmaf(hc.w, Wdl[(kb + 11) * 4 + dv], s2);
        s3 = fmaf(hd.x, Wdl[(kb + 12) * 4 + dv], s3);
        s3 = fmaf(hd.y, Wdl[(kb + 13) * 4 + dv], s3);
        s3 = fmaf(hd.z, Wdl[(kb + 14) * 4 + dv], s3);
        s3 = fmaf(hd.w, Wdl[(kb + 15) * 4 + dv], s3);
      }
      dl[((t + 1) & 1) * 512 + tid] = (s0 + s1) + (s2 + s3);
    }
    // relaxed spin (sc1 load: always fresh, NO per-poll L2 inv), then ONE acquire fence
    if (tid == 0) {
      const unsigned int tgt = 32u * (unsigned int)(t + 1);
      while (__hip_atomic_load(myctr, __ATOMIC_RELAXED, __HIP_MEMORY_SCOPE_AGENT) < tgt) {
        __builtin_amdgcn_s_sleep(1);
      }
      __builtin_amdgcn_fence(__ATOMIC_ACQUIRE, "agent");  // single L2 inv per step
    }
    __syncthreads();  // (4) whole block ordered after tid0's acquire
  }

  // ---- epilogue: logits[254] (partials in dl parity 0) and logits[255] ----
  {
    if (tid < 128) {  // P(254) written at window(255) -> parity (255+1)&1 = 0
      float s = dl[tid * 4] + dl[tid * 4 + 1] + dl[tid * 4 + 2] + dl[tid * 4 + 3] + bdv;
      __builtin_nontemporal_store(
          s, &out[((size_t)(grow0 + (tid >> 2)) * Tt + (Tt - 2)) * Vv + vbase + (tid & 3)]);
    }
    // P(255): h[255] lives in hfp buf 255%3 = 0; visible after final barrier's acquire
    const float* hrow = hfp + (size_t)((Tt - 1) % 3) * Bb * Nn + (grow0 + db) * Nn;
    float part = 0.f;
#pragma unroll 8
    for (int k4 = dq * 32; k4 < dq * 32 + 32; ++k4) {
      float4 h4 = ((const float4*)hrow)[k4];
      int kb = k4 * 4;
      part = fmaf(h4.x, Wdl[(kb + 0) * 4 + dv], part);
      part = fmaf(h4.y, Wdl[(kb + 1) * 4 + dv], part);
      part = fmaf(h4.z, Wdl[(kb + 2) * 4 + dv], part);
      part = fmaf(h4.w, Wdl[(kb + 3) * 4 + dv], part);
    }
    dl[512 + tid] = part;
    __syncthreads();
    if (tid < 128) {
      float s = dl[512 + tid * 4] + dl[512 + tid * 4 + 1] + dl[512 + tid * 4 + 2] +
                dl[512 + tid * 4 + 3] + bdv;
      __builtin_nontemporal_store(
          s, &out[((size_t)(grow0 + (tid >> 2)) * Tt + (Tt - 1)) * Vv + vbase + (tid & 3)]);
    }
  }
}

extern "C" void kernel_launch(void* const* d_in, const int* in_sizes, int n_in,
                              void* d_out, int out_size, void* d_ws, size_t ws_size,
                              hipStream_t stream) {
  const int* X = (const int*)d_in[0];
  const float* h0 = (const float*)d_in[1];
  const float* c0 = (const float*)d_in[2];
  const float* emb = (const float*)d_in[3];
  const float* Wx = (const float*)d_in[4];
  const float* Wh = (const float*)d_in[5];
  const float* bias = (const float*)d_in[6];
  const float* Wd = (const float*)d_in[7];
  const float* bd = (const float*)d_in[8];
  float* out = (float*)d_out;

  // ws layout: proj 1 MiB | hfp 3x[256][512] f32 (1.5 MiB) | hx 2x[256][512] fp16 (0.5 MiB)
  //          | ctr 256 u32.  Total ~3 MiB.
  float* proj = (float*)d_ws;
  float* hfp = proj + Vv * Gg;
  unsigned short* hx = (unsigned short*)(hfp + 3 * Bb * Nn);
  unsigned int* ctr = (unsigned int*)(hx + 2 * Bb * Nn);

  proj_kernel<<<dim3(Vv), dim3(256), 0, stream>>>(emb, Wx, bias, proj, ctr);

  void* args[] = {(void*)&X,   (void*)&h0, (void*)&c0,   (void*)&Wh,
                  (void*)&Wd,  (void*)&bd, (void*)&proj, (void*)&hfp,
                  (void*)&hx,  (void*)&ctr, (void*)&out};
  hipLaunchCooperativeKernel((const void*)lstm_kernel, dim3(256), dim3(512), args,
                             (unsigned int)65536, stream);
}

// Round 7
// 1378.345 us; speedup vs baseline: 2.5670x; 2.5670x over previous
//
#include <hip/hip_runtime.h>

#define Bb 256
#define Tt 256
#define Ee 64
#define Nn 512
#define Vv 128
#define Gg 2048  // 4*N

typedef __attribute__((ext_vector_type(8))) _Float16 fp16x8;
typedef __attribute__((ext_vector_type(4))) float f32x4;

__device__ __forceinline__ unsigned short f2h(float f) {  // fp32 -> fp16 bits (RTE)
  union { _Float16 h; unsigned short u; } cv;
  cv.h = (_Float16)f;
  return cv.u;
}

// agent-scope (sc1) ops: bypass L1/L2, serviced at the coherent memory-side L3.
__device__ __forceinline__ unsigned long long ldg_agent(const unsigned long long* p) {
  return __hip_atomic_load(p, __ATOMIC_RELAXED, __HIP_MEMORY_SCOPE_AGENT);
}
__device__ __forceinline__ void stg_agent(unsigned int* p, unsigned int v) {
  __hip_atomic_store(p, v, __ATOMIC_RELAXED, __HIP_MEMORY_SCOPE_AGENT);
}

__device__ __forceinline__ float sigm_fast(float x) { return 1.f / (1.f + __expf(-x)); }
__device__ __forceinline__ float tanh_fast(float x) { return 1.f - 2.f / (1.f + __expf(2.f * x)); }

// Kernel 1: proj[v][g] = bias[g] + sum_e emb[v][e]*Wx[e][g]; also zero barrier ctrs.
__global__ void proj_kernel(const float* __restrict__ emb, const float* __restrict__ Wx,
                            const float* __restrict__ bias, float* __restrict__ proj,
                            unsigned int* __restrict__ ctr) {
  const int v = blockIdx.x;
  __shared__ float el[Ee];
  if (threadIdx.x < Ee) el[threadIdx.x] = emb[v * Ee + threadIdx.x];
  __syncthreads();
  for (int g = threadIdx.x; g < Gg; g += blockDim.x) {
    float s = bias[g];
#pragma unroll
    for (int e = 0; e < Ee; ++e) s = fmaf(el[e], Wx[e * Gg + g], s);
    proj[v * Gg + g] = s;
  }
  if (v == 0) ctr[threadIdx.x] = 0u;  // re-zeroed EVERY launch (d_ws poisoned 0xAA)
}

// Kernel 2: persistent LSTM. 256 blocks x 512 threads, cooperative.
// block -> (bg = blockIdx&7: batch rows [bg*32,+32)) x (nc = blockIdx>>3: hidden [nc*16,+16))
// 8 independent recurrences; per-step 32-block group barrier.
//
// ROUND-7 SYNC DESIGN (post-mortem of round 6: WRITE_SIZE=290MB @95GB/s == dur; the
// RELEASE/ACQUIRE pair emitted per-step buffer_wbl2+inv, flushing all h state to HBM):
//   - cross-block h flows ONLY through relaxed agent-scope (sc1) atomics -> L3-resident,
//     never dirty in L2 -> no wbl2/inv fences anywhere in the loop.
//   - ordering: __syncthreads (vmcnt(0): h stores acked at L3) -> relaxed add -> peers'
//     relaxed sc1 spin/load observe counter then data, all at the single L3 order point.
//   - read-only data (proj/X/Wd/Wh) stays normally cached in L1/L2 across steps now.
//
// Buffering proof: staging(t) reads hx[(t-1)&1] BEFORE our release-add(t); a peer can
// first clobber that buffer at its gate-update(t+1), which requires barrier(t) completion,
// which requires OUR add(t). Two buffers suffice. Dense GEMM reads h[t-1] from LDS hl
// (valid sync1(t)..staging(t+1)), not from global.
//
// LDS time-share (64 KB): phase 1: Whs 64 KB. phase 2: hl 32K | zl 8.5K | dl 4K | Wdl 10K.
__launch_bounds__(512, 2)
__global__ void lstm_kernel(const int* __restrict__ X, const float* __restrict__ h0,
                            const float* __restrict__ c0, const float* __restrict__ Wh,
                            const float* __restrict__ Wd, const float* __restrict__ bd,
                            const float* __restrict__ proj, unsigned short* __restrict__ hx,
                            unsigned int* __restrict__ ctr, float* __restrict__ out) {
  extern __shared__ char smem[];
  short* Whs = (short*)smem;             // phase 1: [64 col][64 slot][8] fp16 (64 KB)
  short* hl  = (short*)smem;             // phase 2: [32 row][64 slot][8] fp16 (32 KB)
  float* zl  = (float*)(smem + 32768);   // phase 2: [32][68] f32 z tile      (8704 B)
  float* dl  = (float*)(smem + 41472);   // phase 2: [2][512] f32 dense scratch (4 KB)
  float* Wdl = (float*)(smem + 45568);   // phase 2: [512 k][5] f32 padded    (10240 B)

  const int tid = threadIdx.x;
  const int bg = blockIdx.x & 7;
  const int nc = blockIdx.x >> 3;
  const int nbase = nc << 4;
  const int vbase = nc << 2;
  const int grow0 = bg << 5;

  // ---- phase 1: Wh slice -> LDS fp16, swizzled [col][k8^(col&7)][k&7] ----
  for (int i = tid; i < 64 * 512; i += 512) {
    int col = i & 63;
    int k = i >> 6;
    int zc = (col >> 4) * Nn + nbase + (col & 15);  // gate*N + nbase + nl
    unsigned short w = f2h(Wh[k * Gg + zc]);
    int unit = col * 64 + ((k >> 3) ^ (col & 7));
    ((unsigned short*)Whs)[unit * 8 + (k & 7)] = w;
  }
  __syncthreads();

  // mfma ids: 8 waves = 2 b-tiles x 4 gates
  const int w = tid >> 6, lane = tid & 63;
  const int btile = w & 1, gate = w >> 1;
  const int arow = (btile << 4) + (lane & 15);
  const int bcol = (gate << 4) + (lane & 15);
  const int kg = lane >> 4;

  fp16x8 bfrag[16];
#pragma unroll
  for (int ks = 0; ks < 16; ++ks) {
    int slot = ks * 4 + kg;
    bfrag[ks] = ((const fp16x8*)Whs)[bcol * 64 + (slot ^ (bcol & 7))];
  }
  __syncthreads();  // phase 1 reads done; phase 2 may overwrite smem

  // ---- phase 2 init: Wd slice -> LDS padded [k][5] (16-bank spread, conflict-free) ----
  for (int i = tid; i < 2048; i += 512) {
    int k = i >> 2, dvv = i & 3;
    Wdl[k * 5 + dvv] = Wd[k * Vv + vbase + dvv];
  }

  const int ub = tid >> 4;  // update ids: thread owns one (b,n) cell
  const int un = tid & 15;
  float c = c0[(grow0 + ub) * Nn + nbase + un];

  const int db = tid >> 4, dv = (tid >> 2) & 3, dq = tid & 3;  // dense ids
  const float bdv = bd[vbase + (tid & 3)];
  const int* xrow = X + (grow0 + ub) * Tt;
  unsigned int* const myctr = &ctr[bg * 32];

#pragma unroll 1
  for (int t = 0; t < Tt; ++t) {
    const int curb = t & 1;  // hx buffer parity

    const int vch = xrow[t];  // L1/L2-hit now (no per-step invalidation)
    const float* pr = proj + (size_t)vch * Gg + nbase + un;
    const float p_i = pr[0 * Nn], p_f = pr[1 * Nn], p_g = pr[2 * Nn], p_o = pr[3 * Nn];

    // ---- stage h_prev (fp16) -> hl (swizzled), via sc1 L3 loads ----
    if (t == 0) {
#pragma unroll
      for (int ci = tid; ci < 2048; ci += 512) {
        int row = ci >> 6, slot = ci & 63;
        const float* src = h0 + (grow0 + row) * Nn + slot * 8;
        fp16x8 v;
#pragma unroll
        for (int j = 0; j < 8; ++j) v[j] = (_Float16)src[j];
        ((fp16x8*)hl)[row * 64 + (slot ^ (row & 7))] = v;
      }
    } else {
      const unsigned long long* src =
          (const unsigned long long*)hx + (((size_t)(curb ^ 1) * Bb * Nn) >> 2);
#pragma unroll
      for (int ci = tid; ci < 2048; ci += 512) {
        int row = ci >> 6, slot = ci & 63;
        const unsigned long long* p = src + ((size_t)(grow0 + row) * 64 + slot) * 2;
        unsigned long long lo = ldg_agent(p);
        unsigned long long hi = ldg_agent(p + 1);
        unsigned long long* d =
            (unsigned long long*)hl + ((size_t)row * 64 + (slot ^ (row & 7))) * 2;
        d[0] = lo;
        d[1] = hi;
      }
    }
    __syncthreads();  // (1) hl ready

    // ---- MFMA: z[32b][64c] = h[32b][512k] @ WhSlice ; quad accumulators ----
    f32x4 a0 = {0.f, 0.f, 0.f, 0.f}, a1 = {0.f, 0.f, 0.f, 0.f};
    f32x4 a2 = {0.f, 0.f, 0.f, 0.f}, a3 = {0.f, 0.f, 0.f, 0.f};
#pragma unroll
    for (int ks = 0; ks < 16; ks += 4) {
      fp16x8 h0v = ((const fp16x8*)hl)[arow * 64 + (((ks + 0) * 4 + kg) ^ (arow & 7))];
      fp16x8 h1v = ((const fp16x8*)hl)[arow * 64 + (((ks + 1) * 4 + kg) ^ (arow & 7))];
      fp16x8 h2v = ((const fp16x8*)hl)[arow * 64 + (((ks + 2) * 4 + kg) ^ (arow & 7))];
      fp16x8 h3v = ((const fp16x8*)hl)[arow * 64 + (((ks + 3) * 4 + kg) ^ (arow & 7))];
      a0 = __builtin_amdgcn_mfma_f32_16x16x32_f16(h0v, bfrag[ks + 0], a0, 0, 0, 0);
      a1 = __builtin_amdgcn_mfma_f32_16x16x32_f16(h1v, bfrag[ks + 1], a1, 0, 0, 0);
      a2 = __builtin_amdgcn_mfma_f32_16x16x32_f16(h2v, bfrag[ks + 2], a2, 0, 0, 0);
      a3 = __builtin_amdgcn_mfma_f32_16x16x32_f16(h3v, bfrag[ks + 3], a3, 0, 0, 0);
    }
#pragma unroll
    for (int j = 0; j < 4; ++j)
      zl[((btile << 4) + ((lane >> 4) << 2) + j) * 68 + (gate << 4) + (lane & 15)] =
          (a0[j] + a1[j]) + (a2[j] + a3[j]);
    __syncthreads();  // (2) zl ready

    // ---- gate update (fp32); h -> hx[t&1] via paired sc1 u32 store ----
    {
      float zi = zl[ub * 68 + 0 + un] + p_i;
      float zf = zl[ub * 68 + 16 + un] + p_f;
      float zg = zl[ub * 68 + 32 + un] + p_g;
      float zo = zl[ub * 68 + 48 + un] + p_o;
      float ii = sigm_fast(zi);
      float ff = sigm_fast(zf);
      float gg = tanh_fast(zg);
      float oo = sigm_fast(zo);
      c = ff * c + ii * gg;
      float h = oo * tanh_fast(c);
      unsigned int hb = f2h(h);
      unsigned int nb = __shfl_xor(hb, 1);  // partner cell (un^1), same batch row
      if (!(lane & 1)) {
        size_t off = (size_t)curb * Bb * Nn + (size_t)(grow0 + ub) * Nn + nbase + un;
        stg_agent((unsigned int*)hx + (off >> 1), hb | (nb << 16));
      }
    }
    __syncthreads();  // (3) h stores acked at L3 (vmcnt 0) before the signal

    // ==== barrier window: relaxed signal -> useful work -> relaxed spin. NO fences. ====
    if (tid == 0) {
      __hip_atomic_fetch_add(myctr, 1u, __ATOMIC_RELAXED, __HIP_MEMORY_SCOPE_AGENT);
    }
    // dense finalize: logits[t-2] (partials P(t-2) in dl parity t&1)
    if (t >= 2 && tid < 128) {
      const float* dlR = dl + (t & 1) * 512;
      float s = dlR[tid * 4] + dlR[tid * 4 + 1] + dlR[tid * 4 + 2] + dlR[tid * 4 + 3] + bdv;
      __builtin_nontemporal_store(
          s, &out[((size_t)(grow0 + (tid >> 2)) * Tt + (t - 2)) * Vv + vbase + (tid & 3)]);
    }
    // dense partials: P(t-1) = h[t-1] @ Wd, h[t-1] read from LDS hl (fp16)
    if (t >= 1) {
      const unsigned long long* hlq = (const unsigned long long*)hl;
      float s0 = 0.f, s1 = 0.f, s2 = 0.f, s3 = 0.f;
#pragma unroll 8
      for (int m = 0; m < 32; ++m) {
        int u = dq + (m << 2);                      // u64 chunk 0..127 of this row
        int sx = (u >> 1) ^ (db & 7);               // swizzled 16B-slot
        union { unsigned long long q; _Float16 h4[4]; } r;
        r.q = hlq[(((size_t)db << 6) + sx) * 2 + (u & 1)];
        int wb = 20 * u + dv;                       // Wdl [k][5]: 16-bank spread
        s0 = fmaf((float)r.h4[0], Wdl[wb + 0], s0);
        s1 = fmaf((float)r.h4[1], Wdl[wb + 5], s1);
        s2 = fmaf((float)r.h4[2], Wdl[wb + 10], s2);
        s3 = fmaf((float)r.h4[3], Wdl[wb + 15], s3);
      }
      dl[((t + 1) & 1) * 512 + tid] = (s0 + s1) + (s2 + s3);
    }
    if (tid == 0) {
      const unsigned int tgt = 32u * (unsigned int)(t + 1);
      while (__hip_atomic_load(myctr, __ATOMIC_RELAXED, __HIP_MEMORY_SCOPE_AGENT) < tgt) {
        __builtin_amdgcn_s_sleep(1);
      }
    }
    __syncthreads();  // (4) block proceeds; peers' h[t] visible via sc1 reads at L3
  }

  // ---- epilogue: logits[254] (dl parity 0) and logits[255] (hx buf 1 via sc1) ----
  {
    if (tid < 128) {
      float s = dl[tid * 4] + dl[tid * 4 + 1] + dl[tid * 4 + 2] + dl[tid * 4 + 3] + bdv;
      __builtin_nontemporal_store(
          s, &out[((size_t)(grow0 + (tid >> 2)) * Tt + (Tt - 2)) * Vv + vbase + (tid & 3)]);
    }
    const unsigned long long* hq = (const unsigned long long*)hx +
                                   (((size_t)((Tt - 1) & 1) * Bb * Nn) >> 2) +
                                   ((size_t)(grow0 + db) * Nn >> 2);
    float s0 = 0.f, s1 = 0.f, s2 = 0.f, s3 = 0.f;
#pragma unroll 8
    for (int m = 0; m < 32; ++m) {
      int u = dq + (m << 2);
      union { unsigned long long q; _Float16 h4[4]; } r;
      r.q = ldg_agent(&hq[u]);
      int wb = 20 * u + dv;
      s0 = fmaf((float)r.h4[0], Wdl[wb + 0], s0);
      s1 = fmaf((float)r.h4[1], Wdl[wb + 5], s1);
      s2 = fmaf((float)r.h4[2], Wdl[wb + 10], s2);
      s3 = fmaf((float)r.h4[3], Wdl[wb + 15], s3);
    }
    dl[512 + tid] = (s0 + s1) + (s2 + s3);
    __syncthreads();
    if (tid < 128) {
      float s = dl[512 + tid * 4] + dl[512 + tid * 4 + 1] + dl[512 + tid * 4 + 2] +
                dl[512 + tid * 4 + 3] + bdv;
      __builtin_nontemporal_store(
          s, &out[((size_t)(grow0 + (tid >> 2)) * Tt + (Tt - 1)) * Vv + vbase + (tid & 3)]);
    }
  }
}

extern "C" void kernel_launch(void* const* d_in, const int* in_sizes, int n_in,
                              void* d_out, int out_size, void* d_ws, size_t ws_size,
                              hipStream_t stream) {
  const int* X = (const int*)d_in[0];
  const float* h0 = (const float*)d_in[1];
  const float* c0 = (const float*)d_in[2];
  const float* emb = (const float*)d_in[3];
  const float* Wx = (const float*)d_in[4];
  const float* Wh = (const float*)d_in[5];
  const float* bias = (const float*)d_in[6];
  const float* Wd = (const float*)d_in[7];
  const float* bd = (const float*)d_in[8];
  float* out = (float*)d_out;

  // ws: proj 1 MiB | hx 2x[256][512] fp16 (512 KiB) | ctr 256 u32 (1 KiB)
  float* proj = (float*)d_ws;
  unsigned short* hx = (unsigned short*)(proj + Vv * Gg);
  unsigned int* ctr = (unsigned int*)(hx + 2 * Bb * Nn);

  proj_kernel<<<dim3(Vv), dim3(256), 0, stream>>>(emb, Wx, bias, proj, ctr);

  void* args[] = {(void*)&X,  (void*)&h0,   (void*)&c0, (void*)&Wh, (void*)&Wd,
                  (void*)&bd, (void*)&proj, (void*)&hx, (void*)&ctr, (void*)&out};
  hipLaunchCooperativeKernel((const void*)lstm_kernel, dim3(256), dim3(512), args,
                             (unsigned int)65536, stream);
}

// Round 9
// 1249.616 us; speedup vs baseline: 2.8314x; 1.1030x over previous
//
#include <hip/hip_runtime.h>

#define Bb 256
#define Tt 256
#define Ee 64
#define Nn 512
#define Vv 128
#define Gg 2048  // 4*N

typedef __attribute__((ext_vector_type(8))) _Float16 fp16x8;
typedef __attribute__((ext_vector_type(2))) _Float16 h2;
typedef __attribute__((ext_vector_type(4))) float f32x4;

#if defined(__has_builtin)
#if __has_builtin(__builtin_amdgcn_fdot2)
#define FDOT2(a, b, c) __builtin_amdgcn_fdot2((a), (b), (c), false)
#endif
#endif
#ifndef FDOT2
#define FDOT2(a, b, c) fmaf((float)(a)[0], (float)(b)[0], fmaf((float)(a)[1], (float)(b)[1], (c)))
#endif

__device__ __forceinline__ unsigned short f2h(float f) {  // fp32 -> fp16 bits (RTE)
  union { _Float16 h; unsigned short u; } cv;
  cv.h = (_Float16)f;
  return cv.u;
}

// agent-scope (sc1) ops: bypass L1/L2, serviced at the coherent memory-side L3.
__device__ __forceinline__ unsigned long long ldg_agent(const unsigned long long* p) {
  return __hip_atomic_load(p, __ATOMIC_RELAXED, __HIP_MEMORY_SCOPE_AGENT);
}
__device__ __forceinline__ unsigned int ldg_agent32(const unsigned int* p) {
  return __hip_atomic_load(p, __ATOMIC_RELAXED, __HIP_MEMORY_SCOPE_AGENT);
}
__device__ __forceinline__ void stg_agent32(unsigned int* p, unsigned int v) {
  __hip_atomic_store(p, v, __ATOMIC_RELAXED, __HIP_MEMORY_SCOPE_AGENT);
}
__device__ __forceinline__ void stg_agent64(unsigned long long* p, unsigned long long v) {
  __hip_atomic_store(p, v, __ATOMIC_RELAXED, __HIP_MEMORY_SCOPE_AGENT);
}

__device__ __forceinline__ float sigm_fast(float x) { return 1.f / (1.f + __expf(-x)); }
__device__ __forceinline__ float tanh_fast(float x) { return 1.f - 2.f / (1.f + __expf(2.f * x)); }

// Kernel 1: proj[v][g] = bias[g] + sum_e emb[v][e]*Wx[e][g]; also zero barrier flags.
__global__ void proj_kernel(const float* __restrict__ emb, const float* __restrict__ Wx,
                            const float* __restrict__ bias, float* __restrict__ proj,
                            unsigned int* __restrict__ ctr) {
  const int v = blockIdx.x;
  __shared__ float el[Ee];
  if (threadIdx.x < Ee) el[threadIdx.x] = emb[v * Ee + threadIdx.x];
  __syncthreads();
  for (int g = threadIdx.x; g < Gg; g += blockDim.x) {
    float s = bias[g];
#pragma unroll
    for (int e = 0; e < Ee; ++e) s = fmaf(el[e], Wx[e * Gg + g], s);
    proj[v * Gg + g] = s;
  }
  if (v == 0) ctr[threadIdx.x] = 0u;  // re-zeroed EVERY launch (d_ws poisoned 0xAA)
}

// Kernel 2: persistent LSTM. 256 blocks x 512 threads, cooperative.
// block -> (bg = blockIdx&7: batch rows [bg*32,+32)) x (nc = blockIdx>>3: hidden [nc*16,+16))
// 8 independent recurrences; per-step 32-block group barrier.
//
// ROUND-8/9: post-mortem of r7 (1235us, VALUBusy 40%, 32-deep atomic RMW per step):
//  - FLAG-LINE barrier: block nc sc1-stores flags[bg*32+nc]=t+1 (32 words, ONE 128B line,
//    parallel stores); wave0's 32 lanes poll the line with ONE coalesced sc1 load + __all.
//    No atomic RMW serialization, no hot-line contention.
//  - dense partials use v_dot2_f32_f16 (fp16-pair Wd in LDS): 2 MACs/instr, no cvts.
//  - h-store packs 4 cells -> one sc1 u64 store per 4 lanes.
// Ordering: gate h-stores -> __syncthreads (per-wave vmcnt(0): stores acked at L3) ->
// tid0 flag store (same-thread order after barrier) -> peers' sc1 poll sees flag, then
// staging sc1 loads see h (all serviced at the single L3 order point). No fences.
// (Same release mechanism round 7 validated on HW: relaxed signal after __syncthreads.)
//
// Buffering: staging(t) reads hx[(t-1)&1] BEFORE our flag(t); a peer first clobbers that
// buffer at gate(t+1), which needs barrier(t), which needs OUR flag(t). 2 buffers OK.
//
// LDS (64 KB): phase 1: Whs 64K. phase 2: hl 32K | zl 8.5K | dl 4K | Wdh 5K.
__launch_bounds__(512, 2)
__global__ void lstm_kernel(const int* __restrict__ X, const float* __restrict__ h0,
                            const float* __restrict__ c0, const float* __restrict__ Wh,
                            const float* __restrict__ Wd, const float* __restrict__ bd,
                            const float* __restrict__ proj, unsigned short* __restrict__ hx,
                            unsigned int* __restrict__ ctr, float* __restrict__ out) {
  extern __shared__ char smem[];
  short* Whs = (short*)smem;                     // phase 1: [64 col][64 slot][8] fp16 (64 KB)
  short* hl  = (short*)smem;                     // phase 2: [32 row][64 slot][8] fp16 (32 KB)
  float* zl  = (float*)(smem + 32768);           // phase 2: [32][68] f32 z tile (8704 B)
  float* dl  = (float*)(smem + 41472);           // phase 2: [2][512] f32 dense scratch (4 KB)
  unsigned int* Wdh = (unsigned int*)(smem + 45568);  // phase 2: [128 u][2 p][5] fp16x2 (5 KB)

  const int tid = threadIdx.x;
  const int bg = blockIdx.x & 7;
  const int nc = blockIdx.x >> 3;
  const int nbase = nc << 4;
  const int vbase = nc << 2;
  const int grow0 = bg << 5;

  // ---- phase 1: Wh slice -> LDS fp16, swizzled [col][k8^(col&7)][k&7] ----
  for (int i = tid; i < 64 * 512; i += 512) {
    int col = i & 63;
    int k = i >> 6;
    int zc = (col >> 4) * Nn + nbase + (col & 15);  // gate*N + nbase + nl
    unsigned short w = f2h(Wh[k * Gg + zc]);
    int unit = col * 64 + ((k >> 3) ^ (col & 7));
    ((unsigned short*)Whs)[unit * 8 + (k & 7)] = w;
  }
  __syncthreads();

  // mfma ids: 8 waves = 2 b-tiles x 4 gates
  const int w = tid >> 6, lane = tid & 63;
  const int btile = w & 1, gate = w >> 1;
  const int arow = (btile << 4) + (lane & 15);
  const int bcol = (gate << 4) + (lane & 15);
  const int kg = lane >> 4;

  fp16x8 bfrag[16];
#pragma unroll
  for (int ks = 0; ks < 16; ++ks) {
    int slot = ks * 4 + kg;
    bfrag[ks] = ((const fp16x8*)Whs)[bcol * 64 + (slot ^ (bcol & 7))];
  }
  __syncthreads();  // phase 1 reads done; phase 2 may overwrite smem

  // ---- phase 2 init: Wd slice -> LDS as fp16 pairs [u=k/4][pair][5 pad] ----
  for (int i = tid; i < 1024; i += 512) {
    int u = i >> 3, p = (i >> 2) & 1, dvv = i & 3;
    int k0 = 4 * u + 2 * p;
    unsigned int lo = f2h(Wd[k0 * Vv + vbase + dvv]);
    unsigned int hi = f2h(Wd[(k0 + 1) * Vv + vbase + dvv]);
    Wdh[u * 10 + p * 5 + dvv] = lo | (hi << 16);
  }

  const int ub = tid >> 4;  // update ids: thread owns one (b,n) cell
  const int un = tid & 15;
  float c = c0[(grow0 + ub) * Nn + nbase + un];

  const int db = tid >> 4, dv = (tid >> 2) & 3, dq = tid & 3;  // dense ids
  const float bdv = bd[vbase + (tid & 3)];
  const int* xrow = X + (grow0 + ub) * Tt;
  unsigned int* const flags = &ctr[bg * 32];  // one 128B line per group

#pragma unroll 1
  for (int t = 0; t < Tt; ++t) {
    const int curb = t & 1;  // hx buffer parity

    const int vch = xrow[t];  // L1/L2-cached (no invalidation anywhere)
    const float* pr = proj + (size_t)vch * Gg + nbase + un;
    const float p_i = pr[0 * Nn], p_f = pr[1 * Nn], p_g = pr[2 * Nn], p_o = pr[3 * Nn];

    // ---- stage h_prev (fp16) -> hl (swizzled), via sc1 L3 loads ----
    if (t == 0) {
#pragma unroll
      for (int ci = tid; ci < 2048; ci += 512) {
        int row = ci >> 6, slot = ci & 63;
        const float* src = h0 + (grow0 + row) * Nn + slot * 8;
        fp16x8 v;
#pragma unroll
        for (int j = 0; j < 8; ++j) v[j] = (_Float16)src[j];
        ((fp16x8*)hl)[row * 64 + (slot ^ (row & 7))] = v;
      }
    } else {
      const unsigned long long* src =
          (const unsigned long long*)hx + (((size_t)(curb ^ 1) * Bb * Nn) >> 2);
#pragma unroll
      for (int ci = tid; ci < 2048; ci += 512) {
        int row = ci >> 6, slot = ci & 63;
        const unsigned long long* p = src + ((size_t)(grow0 + row) * 64 + slot) * 2;
        unsigned long long lo = ldg_agent(p);
        unsigned long long hi = ldg_agent(p + 1);
        unsigned long long* d =
            (unsigned long long*)hl + ((size_t)row * 64 + (slot ^ (row & 7))) * 2;
        d[0] = lo;
        d[1] = hi;
      }
    }
    __syncthreads();  // (1) hl ready

    // ---- MFMA: z[32b][64c] = h[32b][512k] @ WhSlice ; quad accumulators ----
    f32x4 a0 = {0.f, 0.f, 0.f, 0.f}, a1 = {0.f, 0.f, 0.f, 0.f};
    f32x4 a2 = {0.f, 0.f, 0.f, 0.f}, a3 = {0.f, 0.f, 0.f, 0.f};
#pragma unroll
    for (int ks = 0; ks < 16; ks += 4) {
      fp16x8 h0v = ((const fp16x8*)hl)[arow * 64 + (((ks + 0) * 4 + kg) ^ (arow & 7))];
      fp16x8 h1v = ((const fp16x8*)hl)[arow * 64 + (((ks + 1) * 4 + kg) ^ (arow & 7))];
      fp16x8 h2v = ((const fp16x8*)hl)[arow * 64 + (((ks + 2) * 4 + kg) ^ (arow & 7))];
      fp16x8 h3v = ((const fp16x8*)hl)[arow * 64 + (((ks + 3) * 4 + kg) ^ (arow & 7))];
      a0 = __builtin_amdgcn_mfma_f32_16x16x32_f16(h0v, bfrag[ks + 0], a0, 0, 0, 0);
      a1 = __builtin_amdgcn_mfma_f32_16x16x32_f16(h1v, bfrag[ks + 1], a1, 0, 0, 0);
      a2 = __builtin_amdgcn_mfma_f32_16x16x32_f16(h2v, bfrag[ks + 2], a2, 0, 0, 0);
      a3 = __builtin_amdgcn_mfma_f32_16x16x32_f16(h3v, bfrag[ks + 3], a3, 0, 0, 0);
    }
#pragma unroll
    for (int j = 0; j < 4; ++j)
      zl[((btile << 4) + ((lane >> 4) << 2) + j) * 68 + (gate << 4) + (lane & 15)] =
          (a0[j] + a1[j]) + (a2[j] + a3[j]);
    __syncthreads();  // (2) zl ready

    // ---- gate update (fp32); h -> hx[t&1]: 4 cells packed, one sc1 u64 per 4 lanes ----
    {
      float zi = zl[ub * 68 + 0 + un] + p_i;
      float zf = zl[ub * 68 + 16 + un] + p_f;
      float zg = zl[ub * 68 + 32 + un] + p_g;
      float zo = zl[ub * 68 + 48 + un] + p_o;
      float ii = sigm_fast(zi);
      float ff = sigm_fast(zf);
      float gg = tanh_fast(zg);
      float oo = sigm_fast(zo);
      c = ff * c + ii * gg;
      float h = oo * tanh_fast(c);
      unsigned int hb = f2h(h);
      unsigned int v01 = hb | (__shfl_xor(hb, 1) << 16);              // even lanes: un,un+1
      unsigned long long v03 =
          (unsigned long long)v01 | ((unsigned long long)__shfl_xor(v01, 2) << 32);
      if (!(lane & 3)) {  // un%4==0 -> 8B-aligned
        size_t off = (size_t)curb * Bb * Nn + (size_t)(grow0 + ub) * Nn + nbase + un;
        stg_agent64((unsigned long long*)(hx + off), v03);
      }
    }
    __syncthreads();  // (3) all waves' h stores acked at L3 (vmcnt 0) before the flag

    // ==== barrier window: flag store -> useful work -> 32-lane line poll ====
    if (tid == 0) stg_agent32(&flags[nc], t + 1u);  // ordered after h (same thread)
    // dense finalize: logits[t-2] (partials P(t-2) in dl parity t&1)
    if (t >= 2 && tid < 128) {
      const float* dlR = dl + (t & 1) * 512;
      float s = dlR[tid * 4] + dlR[tid * 4 + 1] + dlR[tid * 4 + 2] + dlR[tid * 4 + 3] + bdv;
      __builtin_nontemporal_store(
          s, &out[((size_t)(grow0 + (tid >> 2)) * Tt + (t - 2)) * Vv + vbase + (tid & 3)]);
    }
    // dense partials: P(t-1) = h[t-1] @ Wd via fdot2, h[t-1] from LDS hl (fp16 pairs)
    if (t >= 1) {
      const unsigned long long* hlq = (const unsigned long long*)hl;
      float s0 = 0.f, s1 = 0.f;
#pragma unroll 8
      for (int m = 0; m < 32; ++m) {
        int u = dq + (m << 2);         // u64 chunk 0..127: k = 4u..4u+3
        int sx = (u >> 1) ^ (db & 7);  // swizzled 16B-slot
        union { unsigned long long q; h2 p[2]; } r;
        r.q = hlq[(((size_t)db << 6) + sx) * 2 + (u & 1)];
        const h2* wp = (const h2*)(Wdh + u * 10 + dv);
        s0 = FDOT2(r.p[0], wp[0], s0);
        s1 = FDOT2(r.p[1], wp[5], s1);
      }
      dl[((t + 1) & 1) * 512 + tid] = s0 + s1;
    }
    // poll: one coalesced sc1 load covers the whole 32-flag line
    if (w == 0) {
      const unsigned int tgt = t + 1u;
      while (true) {
        unsigned int v = (lane < 32) ? ldg_agent32(&flags[lane]) : tgt;
        if (__all(v >= tgt)) break;
        __builtin_amdgcn_s_sleep(1);
      }
    }
    __syncthreads();  // (4) block proceeds; peers' h[t] visible via sc1 reads at L3
  }

  // ---- epilogue: logits[254] (dl parity 0) and logits[255] (hx buf 1 via sc1) ----
  {
    if (tid < 128) {
      float s = dl[tid * 4] + dl[tid * 4 + 1] + dl[tid * 4 + 2] + dl[tid * 4 + 3] + bdv;
      __builtin_nontemporal_store(
          s, &out[((size_t)(grow0 + (tid >> 2)) * Tt + (Tt - 2)) * Vv + vbase + (tid & 3)]);
    }
    const unsigned long long* hq = (const unsigned long long*)hx +
                                   (((size_t)((Tt - 1) & 1) * Bb * Nn) >> 2) +
                                   ((size_t)(grow0 + db) * Nn >> 2);
    float s0 = 0.f, s1 = 0.f;
#pragma unroll 8
    for (int m = 0; m < 32; ++m) {
      int u = dq + (m << 2);
      union { unsigned long long q; h2 p[2]; } r;
      r.q = ldg_agent(&hq[u]);
      const h2* wp = (const h2*)(Wdh + u * 10 + dv);
      s0 = FDOT2(r.p[0], wp[0], s0);
      s1 = FDOT2(r.p[1], wp[5], s1);
    }
    dl[512 + tid] = s0 + s1;
    __syncthreads();
    if (tid < 128) {
      float s = dl[512 + tid * 4] + dl[512 + tid * 4 + 1] + dl[512 + tid * 4 + 2] +
                dl[512 + tid * 4 + 3] + bdv;
      __builtin_nontemporal_store(
          s, &out[((size_t)(grow0 + (tid >> 2)) * Tt + (Tt - 1)) * Vv + vbase + (tid & 3)]);
    }
  }
}

extern "C" void kernel_launch(void* const* d_in, const int* in_sizes, int n_in,
                              void* d_out, int out_size, void* d_ws, size_t ws_size,
                              hipStream_t stream) {
  const int* X = (const int*)d_in[0];
  const float* h0 = (const float*)d_in[1];
  const float* c0 = (const float*)d_in[2];
  const float* emb = (const float*)d_in[3];
  const float* Wx = (const float*)d_in[4];
  const float* Wh = (const float*)d_in[5];
  const float* bias = (const float*)d_in[6];
  const float* Wd = (const float*)d_in[7];
  const float* bd = (const float*)d_in[8];
  float* out = (float*)d_out;

  // ws: proj 1 MiB | hx 2x[256][512] fp16 (512 KiB) | flags 256 u32 (1 KiB)
  float* proj = (float*)d_ws;
  unsigned short* hx = (unsigned short*)(proj + Vv * Gg);
  unsigned int* ctr = (unsigned int*)(hx + 2 * Bb * Nn);

  proj_kernel<<<dim3(Vv), dim3(256), 0, stream>>>(emb, Wx, bias, proj, ctr);

  void* args[] = {(void*)&X,  (void*)&h0,   (void*)&c0, (void*)&Wh, (void*)&Wd,
                  (void*)&bd, (void*)&proj, (void*)&hx, (void*)&ctr, (void*)&out};
  hipLaunchCooperativeKernel((const void*)lstm_kernel, dim3(256), dim3(512), args,
                             (unsigned int)65536, stream);
}